// Round 1
// baseline (2916.477 us; speedup 1.0000x reference)
//
#include <hip/hip_runtime.h>
#include <stdint.h>

#define NT 8192      // tokens = 4*2048
#define HD 1024      // hidden
#define FF 4096
#define NE 8

typedef __attribute__((ext_vector_type(4))) float v4f;
typedef __attribute__((ext_vector_type(8))) short v8s;

__device__ __forceinline__ unsigned short f2bf(float f) {
    union { float f; uint32_t u; } v; v.f = f;
    uint32_t r = v.u + 0x7FFFu + ((v.u >> 16) & 1u);
    return (unsigned short)(r >> 16);
}
__device__ __forceinline__ float bf2f(unsigned short h) {
    union { uint32_t u; float f; } v; v.u = ((uint32_t)h) << 16;
    return v.f;
}
__device__ __forceinline__ uint32_t pk2(unsigned short a, unsigned short b) {
    return (uint32_t)a | ((uint32_t)b << 16);
}

// ---------------- router: logits, softmax, top2, lists, losses, x->bf16 ----------------
__global__ __launch_bounds__(256) void router_kernel(
    const float* __restrict__ x, const float* __restrict__ wr,
    int* __restrict__ cnt, float* __restrict__ probs_sum, float* __restrict__ z_sum,
    int* __restrict__ idx_list, float* __restrict__ w_list,
    unsigned short* __restrict__ xb)
{
    int wave = threadIdx.x >> 6, lane = threadIdx.x & 63;
    int t = blockIdx.x * 4 + wave;
    const float* xr = x + (size_t)t * HD;
    float l[NE];
#pragma unroll
    for (int e = 0; e < NE; e++) l[e] = 0.f;
#pragma unroll
    for (int c = 0; c < 4; c++) {
        int idx4 = c * 64 + lane;                 // float4 index within row
        v4f xv = ((const v4f*)xr)[idx4];
        int h0 = idx4 * 4;
        // cast x row to bf16 (8B per lane per chunk)
        ushort4 bb;
        bb.x = f2bf(xv[0]); bb.y = f2bf(xv[1]); bb.z = f2bf(xv[2]); bb.w = f2bf(xv[3]);
        ((ushort4*)(xb + (size_t)t * HD))[idx4] = bb;
#pragma unroll
        for (int j = 0; j < 4; j++) {
            const float* wrow = wr + (size_t)(h0 + j) * NE;
            v4f wa = ((const v4f*)wrow)[0];
            v4f wb = ((const v4f*)wrow)[1];
            float xx = xv[j];
            l[0] += xx * wa[0]; l[1] += xx * wa[1]; l[2] += xx * wa[2]; l[3] += xx * wa[3];
            l[4] += xx * wb[0]; l[5] += xx * wb[1]; l[6] += xx * wb[2]; l[7] += xx * wb[3];
        }
    }
#pragma unroll
    for (int e = 0; e < NE; e++) {
#pragma unroll
        for (int off = 32; off >= 1; off >>= 1) l[e] += __shfl_xor(l[e], off);
    }
    if (lane == 0) {
        float mx = l[0];
#pragma unroll
        for (int e = 1; e < NE; e++) mx = fmaxf(mx, l[e]);
        float p[NE]; float s = 0.f;
#pragma unroll
        for (int e = 0; e < NE; e++) { p[e] = __expf(l[e] - mx); s += p[e]; }
        float inv = 1.f / s;
#pragma unroll
        for (int e = 0; e < NE; e++) p[e] *= inv;
        int i1 = 0;
#pragma unroll
        for (int e = 1; e < NE; e++) if (p[e] > p[i1]) i1 = e;
        int i2 = (i1 == 0) ? 1 : 0;
#pragma unroll
        for (int e = 0; e < NE; e++) if (e != i1 && p[e] > p[i2]) i2 = e;
        float d = p[i1] + p[i2];
        float w1 = p[i1] / d, w2 = p[i2] / d;
        int pos1 = atomicAdd(&cnt[i1], 1);
        idx_list[i1 * NT + pos1] = t; w_list[i1 * NT + pos1] = w1;
        int pos2 = atomicAdd(&cnt[i2], 1);
        idx_list[i2 * NT + pos2] = t; w_list[i2 * NT + pos2] = w2;
        float zz = 0.f;
#pragma unroll
        for (int e = 0; e < NE; e++) zz += l[e] * l[e];
        atomicAdd(z_sum, zz);
#pragma unroll
        for (int e = 0; e < NE; e++) atomicAdd(&probs_sum[e], p[e]);
    }
}

// ---------------- losses ----------------
__global__ void loss_kernel(const float* __restrict__ probs_sum,
                            const float* __restrict__ z_sum,
                            float* __restrict__ out)
{
    if (threadIdx.x == 0 && blockIdx.x == 0) {
        float z = 8.f * z_sum[0] / (float)(NT * NE);
        float s = 0.f;
        for (int e = 0; e < NE; e++) {
            float pm = probs_sum[e] / (float)NT;
            s += pm * logf(pm + 1e-9f);
        }
        out[(size_t)NT * HD]     = z;       // router_z_loss = 8 * mean(logits^2)
        out[(size_t)NT * HD + 1] = 8.f * s; // router_aux_loss = 8 * sum_e pm*log(pm+1e-9)
    }
}

// ---------------- grouped GEMM, one expert per launch ----------------
// MODE 0: H = silu(Xg @ Wg)          A = x_bf16 gathered, B = w_gate[e] (fp32, KxN)
// MODE 1: H = H * (Xg @ Wu)          A = x_bf16 gathered, B = w_up[e]
// MODE 2: out[tok] += w * (H @ Wd)   A = Hbuf rows,       B = w_down[e]
template<int MODE>
__global__ __launch_bounds__(256) void gemm_kernel(
    const float* __restrict__ Bglob, const int* __restrict__ cnt,
    const int* __restrict__ idx_list, const float* __restrict__ w_list,
    const unsigned short* __restrict__ xb, unsigned short* __restrict__ Hbuf,
    float* __restrict__ out, int e)
{
    constexpr int BM = 128;
    constexpr int BN = (MODE == 2) ? 64 : 128;
    constexpr int BK = 64;
    constexpr int KTOT = (MODE == 2) ? FF : HD;
    constexpr int NTOT = (MODE == 2) ? HD : FF;   // B row stride (elements)
    constexpr int WN = BN / 2;
    constexpr int FN = WN / 16;                   // frags along n per wave
    constexpr int LDA = 72;                       // padded LDS stride (bf16 elems); 144B = 16-aligned, 2-way-bank-free

    __shared__ unsigned short Asm[BM * LDA];
    __shared__ unsigned short Bsm[BN * LDA];
    __shared__ int   toks[BM];
    __shared__ float wgt[BM];

    int n_e = cnt[e];
    int m0 = blockIdx.y * BM;
    if (m0 >= n_e) return;
    int n0 = blockIdx.x * BN;
    int tid = threadIdx.x;
    int lane = tid & 63, wave = tid >> 6;
    int wm = wave >> 1, wn = wave & 1;

    if (tid < BM) {
        int r = m0 + tid;
        toks[tid] = idx_list[e * NT + ((r < n_e) ? r : 0)];
        wgt[tid]  = (r < n_e) ? w_list[e * NT + r] : 0.f;
    }
    __syncthreads();

    const float* Bg = Bglob + (size_t)e * KTOT * NTOT + n0;

    v4f acc[4][FN];
#pragma unroll
    for (int i = 0; i < 4; i++)
#pragma unroll
        for (int j = 0; j < FN; j++) acc[i][j] = (v4f){0.f, 0.f, 0.f, 0.f};

    int am = tid >> 1, ah = tid & 1;              // A staging: row, half (32 elems)
    const unsigned short* Arow;
    if (MODE < 2) Arow = xb + (size_t)toks[am] * HD;
    else          Arow = Hbuf + (size_t)(m0 + am) * FF;  // rows >= n_e: poison, finite, unused

    for (int k0 = 0; k0 < KTOT; k0 += BK) {
        // ---- stage A (bf16, already K-contiguous) ----
        {
            const uint4* src = (const uint4*)(Arow + k0 + ah * 32);
            uint4* dst = (uint4*)(Asm + am * LDA + ah * 32);
#pragma unroll
            for (int j = 0; j < 4; j++) dst[j] = src[j];
        }
        // ---- stage B (fp32 -> bf16, transpose to [n][k]) ----
        if (MODE < 2) {
            int n = (tid & 31) * 4, kg = tid >> 5;        // 8 k-rows each
            const float* bp = Bg + (size_t)(k0 + kg * 8) * NTOT + n;
            v4f r[8];
#pragma unroll
            for (int kk = 0; kk < 8; kk++) r[kk] = *(const v4f*)(bp + (size_t)kk * NTOT);
#pragma unroll
            for (int c = 0; c < 4; c++) {
                uint4 pkd;
                pkd.x = pk2(f2bf(r[0][c]), f2bf(r[1][c]));
                pkd.y = pk2(f2bf(r[2][c]), f2bf(r[3][c]));
                pkd.z = pk2(f2bf(r[4][c]), f2bf(r[5][c]));
                pkd.w = pk2(f2bf(r[6][c]), f2bf(r[7][c]));
                *(uint4*)(Bsm + (n + c) * LDA + kg * 8) = pkd;
            }
        } else {
            int n = (tid & 15) * 4, kg = tid >> 4;        // 4 k-rows each
            const float* bp = Bg + (size_t)(k0 + kg * 4) * NTOT + n;
            v4f r[4];
#pragma unroll
            for (int kk = 0; kk < 4; kk++) r[kk] = *(const v4f*)(bp + (size_t)kk * NTOT);
#pragma unroll
            for (int c = 0; c < 4; c++) {
                uint2 p2;
                p2.x = pk2(f2bf(r[0][c]), f2bf(r[1][c]));
                p2.y = pk2(f2bf(r[2][c]), f2bf(r[3][c]));
                *(uint2*)(Bsm + (n + c) * LDA + kg * 4) = p2;
            }
        }
        __syncthreads();
        // ---- MFMA ----
        int q = lane >> 4, ln = lane & 15;
#pragma unroll
        for (int ks = 0; ks < 2; ks++) {
            v8s a[4], b[FN];
#pragma unroll
            for (int i = 0; i < 4; i++)
                a[i] = *(const v8s*)(Asm + (wm * 64 + i * 16 + ln) * LDA + ks * 32 + q * 8);
#pragma unroll
            for (int j = 0; j < FN; j++)
                b[j] = *(const v8s*)(Bsm + (wn * WN + j * 16 + ln) * LDA + ks * 32 + q * 8);
#pragma unroll
            for (int i = 0; i < 4; i++)
#pragma unroll
                for (int j = 0; j < FN; j++)
                    acc[i][j] = __builtin_amdgcn_mfma_f32_16x16x32_bf16(a[i], b[j], acc[i][j], 0, 0, 0);
        }
        __syncthreads();
    }

    // ---- epilogue ----  D layout: col = lane&15, row = (lane>>4)*4 + reg
    int q = lane >> 4, ln = lane & 15;
#pragma unroll
    for (int i = 0; i < 4; i++) {
#pragma unroll
        for (int j = 0; j < FN; j++) {
#pragma unroll
            for (int r = 0; r < 4; r++) {
                int lm = wm * 64 + i * 16 + q * 4 + r;   // row within tile
                int gm = m0 + lm;
                int gn = n0 + wn * WN + j * 16 + ln;
                if (gm < n_e) {
                    float v = acc[i][j][r];
                    if (MODE == 0) {
                        float sg = v / (1.f + __expf(-v));
                        Hbuf[(size_t)gm * FF + gn] = f2bf(sg);
                    } else if (MODE == 1) {
                        float g = bf2f(Hbuf[(size_t)gm * FF + gn]);
                        Hbuf[(size_t)gm * FF + gn] = f2bf(g * v);
                    } else {
                        int tk = toks[lm];
                        out[(size_t)tk * HD + gn] += wgt[lm] * v;
                    }
                }
            }
        }
    }
}

extern "C" void kernel_launch(void* const* d_in, const int* in_sizes, int n_in,
                              void* d_out, int out_size, void* d_ws, size_t ws_size,
                              hipStream_t stream)
{
    const float* x  = (const float*)d_in[0];
    const float* wr = (const float*)d_in[1];
    const float* wg = (const float*)d_in[2];
    const float* wu = (const float*)d_in[3];
    const float* wd = (const float*)d_in[4];
    float* out = (float*)d_out;

    char* ws = (char*)d_ws;
    int*   cnt       = (int*)ws;                    // 8 ints
    float* probs_sum = (float*)(ws + 32);           // 8 floats
    float* z_sum     = (float*)(ws + 64);           // 1 float
    int*   idx_list  = (int*)(ws + 256);            // 8*8192 ints
    float* w_list    = (float*)(ws + 256 + 262144); // 8*8192 floats
    unsigned short* xb   = (unsigned short*)(ws + 524544);    // 8192*1024 bf16 = 16 MB
    unsigned short* Hbuf = (unsigned short*)(ws + 17301760);  // 8192*4096 bf16 = 64 MB

    hipMemsetAsync(d_ws, 0, 256, stream);
    hipMemsetAsync(d_out, 0, (size_t)out_size * sizeof(float), stream);

    router_kernel<<<NT / 4, 256, 0, stream>>>(x, wr, cnt, probs_sum, z_sum, idx_list, w_list, xb);
    loss_kernel<<<1, 64, 0, stream>>>(probs_sum, z_sum, out);

    for (int e = 0; e < NE; e++) {
        gemm_kernel<0><<<dim3(FF / 128, NT / 128), 256, 0, stream>>>(wg, cnt, idx_list, w_list, xb, Hbuf, out, e);
        gemm_kernel<1><<<dim3(FF / 128, NT / 128), 256, 0, stream>>>(wu, cnt, idx_list, w_list, xb, Hbuf, out, e);
        gemm_kernel<2><<<dim3(HD / 64,  NT / 128), 256, 0, stream>>>(wd, cnt, idx_list, w_list, xb, Hbuf, out, e);
    }
}

// Round 2
// 1769.122 us; speedup vs baseline: 1.6485x; 1.6485x over previous
//
#include <hip/hip_runtime.h>
#include <stdint.h>

#define NT 8192      // tokens = 4*2048
#define HD 1024      // hidden
#define FF 4096
#define NE 8

typedef __attribute__((ext_vector_type(4))) float v4f;
typedef __attribute__((ext_vector_type(8))) short v8s;

__device__ __forceinline__ unsigned short f2bf(float f) {
    union { float f; uint32_t u; } v; v.f = f;
    uint32_t r = v.u + 0x7FFFu + ((v.u >> 16) & 1u);
    return (unsigned short)(r >> 16);
}
__device__ __forceinline__ float bf2f(unsigned short h) {
    union { uint32_t u; float f; } v; v.u = ((uint32_t)h) << 16;
    return v.f;
}
__device__ __forceinline__ uint32_t pk2(unsigned short a, unsigned short b) {
    return (uint32_t)a | ((uint32_t)b << 16);
}

// ---------------- workspace layout (bytes) ----------------
#define WS_CNT   0ull                          // 8 counters spread at stride 32 ints (1 KB)
#define WS_PZ    1024ull                       // 2048 floats  (per-block z partials)
#define WS_PP    (WS_PZ + 8192ull)             // 2048*8 floats (per-block prob partials)
#define WS_IDX   (WS_PP + 65536ull)            // 8*8192 ints
#define WS_WL    (WS_IDX + 262144ull)          // 8*8192 floats
#define WS_XB    (WS_WL + 262144ull)           // 8192*1024 bf16 = 16 MB
#define WS_HBUF  (WS_XB + 16777216ull)         // 8192*4096 bf16 = 64 MB
#define WS_WGB   (WS_HBUF + 67108864ull)       // bf16 [E][FF][HD] transposed gate
#define WS_WUB   (WS_WGB + 67108864ull)        // bf16 [E][FF][HD] transposed up
#define WS_WDB   (WS_WUB + 67108864ull)        // bf16 [E][HD][FF] transposed down
#define WS_PC_END (WS_WDB + 67108864ull)       // ~286 MB

// ---------------- router: logits, softmax, top2, lists, partials, x->bf16 ----------------
__global__ __launch_bounds__(256) void router_kernel(
    const float* __restrict__ x, const float* __restrict__ wr,
    int* __restrict__ cnt, float* __restrict__ pz, float* __restrict__ pp,
    int* __restrict__ idx_list, float* __restrict__ w_list,
    unsigned short* __restrict__ xb)
{
    __shared__ float sp[4][8];
    __shared__ float sz[4];
    __shared__ int   si[4][2];
    __shared__ float sw[4][2];

    int wave = threadIdx.x >> 6, lane = threadIdx.x & 63;
    int t = blockIdx.x * 4 + wave;
    const float* xr = x + (size_t)t * HD;
    float l[NE];
#pragma unroll
    for (int e = 0; e < NE; e++) l[e] = 0.f;
#pragma unroll
    for (int c = 0; c < 4; c++) {
        int idx4 = c * 64 + lane;                 // float4 index within row
        v4f xv = ((const v4f*)xr)[idx4];
        int h0 = idx4 * 4;
        ushort4 bb;
        bb.x = f2bf(xv[0]); bb.y = f2bf(xv[1]); bb.z = f2bf(xv[2]); bb.w = f2bf(xv[3]);
        ((ushort4*)(xb + (size_t)t * HD))[idx4] = bb;
#pragma unroll
        for (int j = 0; j < 4; j++) {
            const float* wrow = wr + (size_t)(h0 + j) * NE;
            v4f wa = ((const v4f*)wrow)[0];
            v4f wb = ((const v4f*)wrow)[1];
            float xx = xv[j];
            l[0] += xx * wa[0]; l[1] += xx * wa[1]; l[2] += xx * wa[2]; l[3] += xx * wa[3];
            l[4] += xx * wb[0]; l[5] += xx * wb[1]; l[6] += xx * wb[2]; l[7] += xx * wb[3];
        }
    }
#pragma unroll
    for (int e = 0; e < NE; e++) {
#pragma unroll
        for (int off = 32; off >= 1; off >>= 1) l[e] += __shfl_xor(l[e], off);
    }
    if (lane == 0) {
        float mx = l[0];
#pragma unroll
        for (int e = 1; e < NE; e++) mx = fmaxf(mx, l[e]);
        float p[NE]; float s = 0.f;
#pragma unroll
        for (int e = 0; e < NE; e++) { p[e] = __expf(l[e] - mx); s += p[e]; }
        float inv = 1.f / s;
        float zz = 0.f;
#pragma unroll
        for (int e = 0; e < NE; e++) { p[e] *= inv; zz += l[e] * l[e]; sp[wave][e] = p[e]; }
        sz[wave] = zz;
        int i1 = 0;
#pragma unroll
        for (int e = 1; e < NE; e++) if (p[e] > p[i1]) i1 = e;
        int i2 = (i1 == 0) ? 1 : 0;
#pragma unroll
        for (int e = 0; e < NE; e++) if (e != i1 && p[e] > p[i2]) i2 = e;
        float d = p[i1] + p[i2];
        si[wave][0] = i1; sw[wave][0] = p[i1] / d;
        si[wave][1] = i2; sw[wave][1] = p[i2] / d;
    }
    __syncthreads();
    int tid = threadIdx.x;
    if (tid < 8)
        pp[blockIdx.x * 8 + tid] = sp[0][tid] + sp[1][tid] + sp[2][tid] + sp[3][tid];
    else if (tid == 8)
        pz[blockIdx.x] = sz[0] + sz[1] + sz[2] + sz[3];
    if (tid == 0) {
        int cl[8] = {0,0,0,0,0,0,0,0};
        int bl[8];
#pragma unroll
        for (int w = 0; w < 4; w++) { cl[si[w][0]]++; cl[si[w][1]]++; }
#pragma unroll
        for (int ee = 0; ee < 8; ee++)
            if (cl[ee]) { bl[ee] = atomicAdd(&cnt[ee * 32], cl[ee]); cl[ee] = 0; }
#pragma unroll
        for (int w = 0; w < 4; w++)
#pragma unroll
            for (int k = 0; k < 2; k++) {
                int ee = si[w][k];
                int pos = bl[ee] + cl[ee]++;
                idx_list[ee * NT + pos] = blockIdx.x * 4 + w;
                w_list[ee * NT + pos]  = sw[w][k];
            }
    }
}

// ---------------- losses: reduce 2048 block partials ----------------
__global__ __launch_bounds__(256) void loss_kernel(
    const float* __restrict__ pz, const float* __restrict__ pp, float* __restrict__ out)
{
    int tid = threadIdx.x;
    float z = 0.f, p[8] = {0.f,0.f,0.f,0.f,0.f,0.f,0.f,0.f};
    for (int b = tid; b < 2048; b += 256) {
        z += pz[b];
#pragma unroll
        for (int e = 0; e < 8; e++) p[e] += pp[b * 8 + e];
    }
#pragma unroll
    for (int off = 32; off >= 1; off >>= 1) {
        z += __shfl_xor(z, off);
#pragma unroll
        for (int e = 0; e < 8; e++) p[e] += __shfl_xor(p[e], off);
    }
    __shared__ float red[4][9];
    int wave = tid >> 6, lane = tid & 63;
    if (lane == 0) {
        red[wave][0] = z;
#pragma unroll
        for (int e = 0; e < 8; e++) red[wave][1 + e] = p[e];
    }
    __syncthreads();
    if (tid == 0) {
        float zz = red[0][0] + red[1][0] + red[2][0] + red[3][0];
        float s = 0.f;
        for (int e = 0; e < 8; e++) {
            float pm = (red[0][1+e] + red[1][1+e] + red[2][1+e] + red[3][1+e]) / (float)NT;
            s += pm * logf(pm + 1e-9f);
        }
        out[(size_t)NT * HD]     = 8.f * zz / (float)(NT * NE);
        out[(size_t)NT * HD + 1] = 8.f * s;
    }
}

// ---------------- weight convert+transpose: fp32 [E][K][N] -> bf16 [E][N][K] ----------------
template<int K, int N>
__global__ __launch_bounds__(256) void conv_kernel(
    const float* __restrict__ src, unsigned short* __restrict__ dst)
{
    __shared__ float t[64][65];
    int tid = threadIdx.x;
    int e = blockIdx.z;
    int r = tid >> 2, q = tid & 3;
    const float* s = src + ((size_t)e * K + blockIdx.y * 64 + r) * N + blockIdx.x * 64 + q * 16;
#pragma unroll
    for (int j = 0; j < 4; j++) {
        v4f v = *(const v4f*)(s + j * 4);
        t[r][q * 16 + j * 4 + 0] = v[0];
        t[r][q * 16 + j * 4 + 1] = v[1];
        t[r][q * 16 + j * 4 + 2] = v[2];
        t[r][q * 16 + j * 4 + 3] = v[3];
    }
    __syncthreads();
    unsigned short b[16];
#pragma unroll
    for (int i = 0; i < 16; i++) b[i] = f2bf(t[q * 16 + i][r]);
    uint4 o0, o1;
    o0.x = pk2(b[0], b[1]);  o0.y = pk2(b[2], b[3]);
    o0.z = pk2(b[4], b[5]);  o0.w = pk2(b[6], b[7]);
    o1.x = pk2(b[8], b[9]);  o1.y = pk2(b[10], b[11]);
    o1.z = pk2(b[12], b[13]); o1.w = pk2(b[14], b[15]);
    unsigned short* d = dst + ((size_t)e * N + blockIdx.x * 64 + r) * K + blockIdx.y * 64 + q * 16;
    *(uint4*)d = o0;
    *(uint4*)(d + 8) = o1;
}

// ---------------- fused gate+up:  Hbuf = silu(Xg@Wg) * (Xg@Wu) ----------------
// BM=128, BN=64 per weight, BK=64. PC: B from bf16 [E][FF][HD] slabs; else fp32 on-the-fly.
template<bool PC>
__global__ __launch_bounds__(256) void gateup_kernel(
    const void* __restrict__ Bg_, const void* __restrict__ Bu_,
    const int* __restrict__ cnt, const int* __restrict__ idx_list,
    const unsigned short* __restrict__ xb, unsigned short* __restrict__ Hbuf, int e)
{
    constexpr int LDA = 72;
    __shared__ unsigned short Asm[128 * LDA];
    __shared__ unsigned short Bsm[2][64 * LDA];
    __shared__ int toks[128];

    int n_e = cnt[e * 32];
    int m0 = blockIdx.y * 128;
    if (m0 >= n_e) return;
    int n0 = blockIdx.x * 64;
    int tid = threadIdx.x, lane = tid & 63, wave = tid >> 6;
    int wm = wave >> 1, wn = wave & 1;

    if (tid < 128) {
        int r = m0 + tid;
        toks[tid] = idx_list[e * NT + ((r < n_e) ? r : 0)];
    }
    __syncthreads();

    v4f acc[2][4][2];
#pragma unroll
    for (int w = 0; w < 2; w++)
#pragma unroll
        for (int i = 0; i < 4; i++)
#pragma unroll
            for (int j = 0; j < 2; j++) acc[w][i][j] = (v4f){0.f, 0.f, 0.f, 0.f};

    int am = tid >> 1, ah = tid & 1;
    const unsigned short* Arow = xb + (size_t)toks[am] * HD;

    for (int k0 = 0; k0 < HD; k0 += 64) {
        {   // stage A (bf16 rows, K-contiguous)
            const uint4* src = (const uint4*)(Arow + k0 + ah * 32);
            uint4* dst = (uint4*)(Asm + am * LDA + ah * 32);
#pragma unroll
            for (int j = 0; j < 4; j++) dst[j] = src[j];
        }
        if constexpr (PC) {     // stage B: pure bf16 copies from transposed slabs
            int r = lane, h = wave;
#pragma unroll
            for (int w = 0; w < 2; w++) {
                const unsigned short* src = (const unsigned short*)(w ? Bu_ : Bg_)
                    + ((size_t)e * FF + n0 + r) * HD + k0 + h * 16;
                *(uint4*)(Bsm[w] + r * LDA + h * 16)     = *(const uint4*)src;
                *(uint4*)(Bsm[w] + r * LDA + h * 16 + 8) = *(const uint4*)(src + 8);
            }
        } else {                // stage B: fp32 -> bf16 transpose on the fly
            int n = (tid & 15) * 4, kg = tid >> 4;
#pragma unroll
            for (int w = 0; w < 2; w++) {
                const float* bp = (const float*)(w ? Bu_ : Bg_)
                    + (size_t)e * HD * FF + (size_t)(k0 + kg * 4) * FF + n0 + n;
                v4f rr[4];
#pragma unroll
                for (int kk = 0; kk < 4; kk++) rr[kk] = *(const v4f*)(bp + (size_t)kk * FF);
#pragma unroll
                for (int c = 0; c < 4; c++) {
                    uint2 p2;
                    p2.x = pk2(f2bf(rr[0][c]), f2bf(rr[1][c]));
                    p2.y = pk2(f2bf(rr[2][c]), f2bf(rr[3][c]));
                    *(uint2*)(Bsm[w] + (n + c) * LDA + kg * 4) = p2;
                }
            }
        }
        __syncthreads();
        {
            int q = lane >> 4, ln = lane & 15;
#pragma unroll
            for (int ks = 0; ks < 2; ks++) {
                v8s a[4], b[2][2];
#pragma unroll
                for (int i = 0; i < 4; i++)
                    a[i] = *(const v8s*)(Asm + (wm * 64 + i * 16 + ln) * LDA + ks * 32 + q * 8);
#pragma unroll
                for (int w = 0; w < 2; w++)
#pragma unroll
                    for (int j = 0; j < 2; j++)
                        b[w][j] = *(const v8s*)(Bsm[w] + (wn * 32 + j * 16 + ln) * LDA + ks * 32 + q * 8);
#pragma unroll
                for (int i = 0; i < 4; i++)
#pragma unroll
                    for (int j = 0; j < 2; j++) {
                        acc[0][i][j] = __builtin_amdgcn_mfma_f32_16x16x32_bf16(a[i], b[0][j], acc[0][i][j], 0, 0, 0);
                        acc[1][i][j] = __builtin_amdgcn_mfma_f32_16x16x32_bf16(a[i], b[1][j], acc[1][i][j], 0, 0, 0);
                    }
            }
        }
        __syncthreads();
    }

    // epilogue: Hbuf = silu(g) * u   (D layout: col = lane&15, row = (lane>>4)*4 + reg)
    int q = lane >> 4, ln = lane & 15;
#pragma unroll
    for (int i = 0; i < 4; i++)
#pragma unroll
        for (int j = 0; j < 2; j++)
#pragma unroll
            for (int r = 0; r < 4; r++) {
                int lm = wm * 64 + i * 16 + q * 4 + r;
                int gm = m0 + lm;
                int gn = n0 + wn * 32 + j * 16 + ln;
                if (gm < n_e) {
                    float g = acc[0][i][j][r];
                    float u = acc[1][i][j][r];
                    float sg = g / (1.f + __expf(-g));
                    Hbuf[(size_t)gm * FF + gn] = f2bf(sg * u);
                }
            }
}

// ---------------- down:  out[tok] += w * (Hbuf @ Wd) ----------------
template<bool PC>
__global__ __launch_bounds__(256) void down_kernel(
    const void* __restrict__ Bd_, const int* __restrict__ cnt,
    const int* __restrict__ idx_list, const float* __restrict__ w_list,
    const unsigned short* __restrict__ Hbuf, float* __restrict__ out, int e)
{
    constexpr int LDA = 72;
    __shared__ unsigned short Asm[128 * LDA];
    __shared__ unsigned short Bsm[64 * LDA];
    __shared__ int   toks[128];
    __shared__ float wgt[128];

    int n_e = cnt[e * 32];
    int m0 = blockIdx.y * 128;
    if (m0 >= n_e) return;
    int n0 = blockIdx.x * 64;
    int tid = threadIdx.x, lane = tid & 63, wave = tid >> 6;
    int wm = wave >> 1, wn = wave & 1;

    if (tid < 128) {
        int r = m0 + tid;
        toks[tid] = idx_list[e * NT + ((r < n_e) ? r : 0)];
        wgt[tid]  = (r < n_e) ? w_list[e * NT + r] : 0.f;
    }
    __syncthreads();

    v4f acc[4][2];
#pragma unroll
    for (int i = 0; i < 4; i++)
#pragma unroll
        for (int j = 0; j < 2; j++) acc[i][j] = (v4f){0.f, 0.f, 0.f, 0.f};

    int am = tid >> 1, ah = tid & 1;
    const unsigned short* Arow = Hbuf + (size_t)(m0 + am) * FF;

    for (int k0 = 0; k0 < FF; k0 += 64) {
        {
            const uint4* src = (const uint4*)(Arow + k0 + ah * 32);
            uint4* dst = (uint4*)(Asm + am * LDA + ah * 32);
#pragma unroll
            for (int j = 0; j < 4; j++) dst[j] = src[j];
        }
        if constexpr (PC) {
            int r = lane, h = wave;
            const unsigned short* src = (const unsigned short*)Bd_
                + ((size_t)e * HD + n0 + r) * FF + k0 + h * 16;
            *(uint4*)(Bsm + r * LDA + h * 16)     = *(const uint4*)src;
            *(uint4*)(Bsm + r * LDA + h * 16 + 8) = *(const uint4*)(src + 8);
        } else {
            int n = (tid & 15) * 4, kg = tid >> 4;
            const float* bp = (const float*)Bd_
                + (size_t)e * FF * HD + (size_t)(k0 + kg * 4) * HD + n0 + n;
            v4f rr[4];
#pragma unroll
            for (int kk = 0; kk < 4; kk++) rr[kk] = *(const v4f*)(bp + (size_t)kk * HD);
#pragma unroll
            for (int c = 0; c < 4; c++) {
                uint2 p2;
                p2.x = pk2(f2bf(rr[0][c]), f2bf(rr[1][c]));
                p2.y = pk2(f2bf(rr[2][c]), f2bf(rr[3][c]));
                *(uint2*)(Bsm + (n + c) * LDA + kg * 4) = p2;
            }
        }
        __syncthreads();
        {
            int q = lane >> 4, ln = lane & 15;
#pragma unroll
            for (int ks = 0; ks < 2; ks++) {
                v8s a[4], b[2];
#pragma unroll
                for (int i = 0; i < 4; i++)
                    a[i] = *(const v8s*)(Asm + (wm * 64 + i * 16 + ln) * LDA + ks * 32 + q * 8);
#pragma unroll
                for (int j = 0; j < 2; j++)
                    b[j] = *(const v8s*)(Bsm + (wn * 32 + j * 16 + ln) * LDA + ks * 32 + q * 8);
#pragma unroll
                for (int i = 0; i < 4; i++)
#pragma unroll
                    for (int j = 0; j < 2; j++)
                        acc[i][j] = __builtin_amdgcn_mfma_f32_16x16x32_bf16(a[i], b[j], acc[i][j], 0, 0, 0);
            }
        }
        __syncthreads();
    }

    int q = lane >> 4, ln = lane & 15;
#pragma unroll
    for (int i = 0; i < 4; i++)
#pragma unroll
        for (int j = 0; j < 2; j++)
#pragma unroll
            for (int r = 0; r < 4; r++) {
                int lm = wm * 64 + i * 16 + q * 4 + r;
                int gm = m0 + lm;
                int gn = n0 + wn * 32 + j * 16 + ln;
                if (gm < n_e) {
                    int tk = toks[lm];
                    out[(size_t)tk * HD + gn] += wgt[lm] * acc[i][j][r];
                }
            }
}

extern "C" void kernel_launch(void* const* d_in, const int* in_sizes, int n_in,
                              void* d_out, int out_size, void* d_ws, size_t ws_size,
                              hipStream_t stream)
{
    const float* x  = (const float*)d_in[0];
    const float* wr = (const float*)d_in[1];
    const float* wg = (const float*)d_in[2];
    const float* wu = (const float*)d_in[3];
    const float* wd = (const float*)d_in[4];
    float* out = (float*)d_out;

    char* ws = (char*)d_ws;
    int*   cnt      = (int*)(ws + WS_CNT);
    float* pz       = (float*)(ws + WS_PZ);
    float* pp       = (float*)(ws + WS_PP);
    int*   idx_list = (int*)(ws + WS_IDX);
    float* w_list   = (float*)(ws + WS_WL);
    unsigned short* xb   = (unsigned short*)(ws + WS_XB);
    unsigned short* Hbuf = (unsigned short*)(ws + WS_HBUF);
    unsigned short* wgb  = (unsigned short*)(ws + WS_WGB);
    unsigned short* wub  = (unsigned short*)(ws + WS_WUB);
    unsigned short* wdb  = (unsigned short*)(ws + WS_WDB);

    bool pc = ws_size >= WS_PC_END;

    hipMemsetAsync(ws + WS_CNT, 0, 1024, stream);
    hipMemsetAsync(d_out, 0, (size_t)out_size * sizeof(float), stream);

    if (pc) {
        conv_kernel<HD, FF><<<dim3(FF / 64, HD / 64, NE), 256, 0, stream>>>(wg, wgb);
        conv_kernel<HD, FF><<<dim3(FF / 64, HD / 64, NE), 256, 0, stream>>>(wu, wub);
        conv_kernel<FF, HD><<<dim3(HD / 64, FF / 64, NE), 256, 0, stream>>>(wd, wdb);
    }

    router_kernel<<<NT / 4, 256, 0, stream>>>(x, wr, cnt, pz, pp, idx_list, w_list, xb);
    loss_kernel<<<1, 256, 0, stream>>>(pz, pp, out);

    for (int e = 0; e < NE; e++) {
        if (pc) {
            gateup_kernel<true><<<dim3(FF / 64, NT / 128), 256, 0, stream>>>(
                wgb, wub, cnt, idx_list, xb, Hbuf, e);
            down_kernel<true><<<dim3(HD / 64, NT / 128), 256, 0, stream>>>(
                wdb, cnt, idx_list, w_list, Hbuf, out, e);
        } else {
            gateup_kernel<false><<<dim3(FF / 64, NT / 128), 256, 0, stream>>>(
                wg, wu, cnt, idx_list, xb, Hbuf, e);
            down_kernel<false><<<dim3(HD / 64, NT / 128), 256, 0, stream>>>(
                wd, cnt, idx_list, w_list, Hbuf, out, e);
        }
    }
}

// Round 3
// 1029.675 us; speedup vs baseline: 2.8324x; 1.7181x over previous
//
#include <hip/hip_runtime.h>
#include <stdint.h>

#define NT 8192      // tokens = 4*2048
#define HD 1024      // hidden
#define FF 4096
#define NE 8
#define TOTROWS (NT * 2)   // total expert-row assignments (top-2)

typedef __attribute__((ext_vector_type(4))) float v4f;
typedef __attribute__((ext_vector_type(8))) short v8s;

__device__ __forceinline__ unsigned short f2bf(float f) {
    union { float f; uint32_t u; } v; v.f = f;
    uint32_t r = v.u + 0x7FFFu + ((v.u >> 16) & 1u);
    return (unsigned short)(r >> 16);
}
__device__ __forceinline__ float bf2f(unsigned short h) {
    union { uint32_t u; float f; } v; v.u = ((uint32_t)h) << 16;
    return v.f;
}
__device__ __forceinline__ uint32_t pk2(unsigned short a, unsigned short b) {
    return (uint32_t)a | ((uint32_t)b << 16);
}

// ---------------- workspace layout (bytes) ----------------
#define WS_CNT   0ull                              // 8 counters at stride 32 ints (1 KB)
#define WS_PZ    1024ull                           // 2048 floats
#define WS_PP    (WS_PZ + 8192ull)                 // 2048*8 floats
#define WS_PLAN  (WS_PP + 65536ull)                // 256 ints: [0]=nmb, [4..12]=offs, [16..]=tb
#define WS_IDX   (WS_PLAN + 1024ull)               // 8*8192 ints
#define WS_SLOT1 (WS_IDX + 262144ull)              // NT ints
#define WS_W1    (WS_SLOT1 + 32768ull)             // NT floats
#define WS_SLOT2 (WS_W1 + 32768ull)                // NT ints
#define WS_W2    (WS_SLOT2 + 32768ull)             // NT floats
#define WS_XB    (WS_W2 + 32768ull)                // NT*HD bf16 = 16 MB
#define WS_HBUF  (WS_XB + 16777216ull)             // TOTROWS*FF bf16 = 134 MB
#define WS_DBUF  (WS_HBUF + 134217728ull)          // TOTROWS*HD bf16 = 33.5 MB
#define WS_WGB   (WS_DBUF + 33554432ull)           // bf16 [E][FF][HD]
#define WS_WUB   (WS_WGB + 67108864ull)            // bf16 [E][FF][HD]
#define WS_WDB   (WS_WUB + 67108864ull)            // bf16 [E][HD][FF]
#define WS_PC_END (WS_WDB + 67108864ull)           // ~368 MB

// ---------------- router ----------------
__global__ __launch_bounds__(256) void router_kernel(
    const float* __restrict__ x, const float* __restrict__ wr,
    int* __restrict__ cnt, float* __restrict__ pz, float* __restrict__ pp,
    int* __restrict__ idx_list,
    int* __restrict__ slot1, float* __restrict__ w1a,
    int* __restrict__ slot2, float* __restrict__ w2a,
    unsigned short* __restrict__ xb)
{
    __shared__ float sp[4][8];
    __shared__ float sz[4];
    __shared__ int   si[4][2];
    __shared__ float sw[4][2];

    int wave = threadIdx.x >> 6, lane = threadIdx.x & 63;
    int t = blockIdx.x * 4 + wave;
    const float* xr = x + (size_t)t * HD;
    float l[NE];
#pragma unroll
    for (int e = 0; e < NE; e++) l[e] = 0.f;
#pragma unroll
    for (int c = 0; c < 4; c++) {
        int idx4 = c * 64 + lane;
        v4f xv = ((const v4f*)xr)[idx4];
        int h0 = idx4 * 4;
        ushort4 bb;
        bb.x = f2bf(xv[0]); bb.y = f2bf(xv[1]); bb.z = f2bf(xv[2]); bb.w = f2bf(xv[3]);
        ((ushort4*)(xb + (size_t)t * HD))[idx4] = bb;
#pragma unroll
        for (int j = 0; j < 4; j++) {
            const float* wrow = wr + (size_t)(h0 + j) * NE;
            v4f wa = ((const v4f*)wrow)[0];
            v4f wb = ((const v4f*)wrow)[1];
            float xx = xv[j];
            l[0] += xx * wa[0]; l[1] += xx * wa[1]; l[2] += xx * wa[2]; l[3] += xx * wa[3];
            l[4] += xx * wb[0]; l[5] += xx * wb[1]; l[6] += xx * wb[2]; l[7] += xx * wb[3];
        }
    }
#pragma unroll
    for (int e = 0; e < NE; e++) {
#pragma unroll
        for (int off = 32; off >= 1; off >>= 1) l[e] += __shfl_xor(l[e], off);
    }
    if (lane == 0) {
        float mx = l[0];
#pragma unroll
        for (int e = 1; e < NE; e++) mx = fmaxf(mx, l[e]);
        float p[NE]; float s = 0.f;
#pragma unroll
        for (int e = 0; e < NE; e++) { p[e] = __expf(l[e] - mx); s += p[e]; }
        float inv = 1.f / s;
        float zz = 0.f;
#pragma unroll
        for (int e = 0; e < NE; e++) { p[e] *= inv; zz += l[e] * l[e]; sp[wave][e] = p[e]; }
        sz[wave] = zz;
        int i1 = 0;
#pragma unroll
        for (int e = 1; e < NE; e++) if (p[e] > p[i1]) i1 = e;
        int i2 = (i1 == 0) ? 1 : 0;
#pragma unroll
        for (int e = 0; e < NE; e++) if (e != i1 && p[e] > p[i2]) i2 = e;
        float d = p[i1] + p[i2];
        si[wave][0] = i1; sw[wave][0] = p[i1] / d;
        si[wave][1] = i2; sw[wave][1] = p[i2] / d;
    }
    __syncthreads();
    int tid = threadIdx.x;
    if (tid < 8)
        pp[blockIdx.x * 8 + tid] = sp[0][tid] + sp[1][tid] + sp[2][tid] + sp[3][tid];
    else if (tid == 8)
        pz[blockIdx.x] = sz[0] + sz[1] + sz[2] + sz[3];
    if (tid == 0) {
        int cl[8] = {0,0,0,0,0,0,0,0};
        int bl[8];
#pragma unroll
        for (int w = 0; w < 4; w++) { cl[si[w][0]]++; cl[si[w][1]]++; }
#pragma unroll
        for (int ee = 0; ee < 8; ee++)
            if (cl[ee]) { bl[ee] = atomicAdd(&cnt[ee * 32], cl[ee]); cl[ee] = 0; }
#pragma unroll
        for (int w = 0; w < 4; w++) {
            int tok = blockIdx.x * 4 + w;
#pragma unroll
            for (int k = 0; k < 2; k++) {
                int ee = si[w][k];
                int pos = bl[ee] + cl[ee]++;
                idx_list[ee * NT + pos] = tok;
                if (k == 0) { slot1[tok] = (ee << 16) | pos; w1a[tok] = sw[w][0]; }
                else        { slot2[tok] = (ee << 16) | pos; w2a[tok] = sw[w][1]; }
            }
        }
    }
}

// ---------------- losses + plan (prefix offsets + m-block table) ----------------
__global__ __launch_bounds__(256) void loss_plan_kernel(
    const float* __restrict__ pz, const float* __restrict__ pp,
    const int* __restrict__ cnt, int* __restrict__ plan, float* __restrict__ out)
{
    int tid = threadIdx.x;
    if (tid == 0) {
        int nm = 0, off = 0;
        for (int e = 0; e < NE; e++) {
            plan[4 + e] = off;
            int c = cnt[e * 32];
            int nb = (c + 127) >> 7;
            for (int mb = 0; mb < nb; mb++) plan[16 + nm++] = (e << 16) | mb;
            off += c;
        }
        plan[4 + NE] = off;
        plan[0] = nm;
    }
    float z = 0.f, p[8] = {0.f,0.f,0.f,0.f,0.f,0.f,0.f,0.f};
    for (int b = tid; b < 2048; b += 256) {
        z += pz[b];
#pragma unroll
        for (int e = 0; e < 8; e++) p[e] += pp[b * 8 + e];
    }
#pragma unroll
    for (int off = 32; off >= 1; off >>= 1) {
        z += __shfl_xor(z, off);
#pragma unroll
        for (int e = 0; e < 8; e++) p[e] += __shfl_xor(p[e], off);
    }
    __shared__ float red[4][9];
    int wave = tid >> 6, lane = tid & 63;
    if (lane == 0) {
        red[wave][0] = z;
#pragma unroll
        for (int e = 0; e < 8; e++) red[wave][1 + e] = p[e];
    }
    __syncthreads();
    if (tid == 0) {
        float zz = red[0][0] + red[1][0] + red[2][0] + red[3][0];
        float s = 0.f;
        for (int e = 0; e < 8; e++) {
            float pm = (red[0][1+e] + red[1][1+e] + red[2][1+e] + red[3][1+e]) / (float)NT;
            s += pm * logf(pm + 1e-9f);
        }
        out[(size_t)NT * HD]     = 8.f * zz / (float)(NT * NE);
        out[(size_t)NT * HD + 1] = 8.f * s;
    }
}

// ---------------- weight convert+transpose: fp32 [E][K][N] -> bf16 [E][N][K] ----------------
template<int K, int N>
__global__ __launch_bounds__(256) void conv_kernel(
    const float* __restrict__ src, unsigned short* __restrict__ dst)
{
    __shared__ float t[64][65];
    int tid = threadIdx.x;
    int e = blockIdx.z;
    int r = tid >> 2, q = tid & 3;
    const float* s = src + ((size_t)e * K + blockIdx.y * 64 + r) * N + blockIdx.x * 64 + q * 16;
#pragma unroll
    for (int j = 0; j < 4; j++) {
        v4f v = *(const v4f*)(s + j * 4);
        t[r][q * 16 + j * 4 + 0] = v[0];
        t[r][q * 16 + j * 4 + 1] = v[1];
        t[r][q * 16 + j * 4 + 2] = v[2];
        t[r][q * 16 + j * 4 + 3] = v[3];
    }
    __syncthreads();
    unsigned short b[16];
#pragma unroll
    for (int i = 0; i < 16; i++) b[i] = f2bf(t[q * 16 + i][r]);
    uint4 o0, o1;
    o0.x = pk2(b[0], b[1]);  o0.y = pk2(b[2], b[3]);
    o0.z = pk2(b[4], b[5]);  o0.w = pk2(b[6], b[7]);
    o1.x = pk2(b[8], b[9]);  o1.y = pk2(b[10], b[11]);
    o1.z = pk2(b[12], b[13]); o1.w = pk2(b[14], b[15]);
    unsigned short* d = dst + ((size_t)e * N + blockIdx.x * 64 + r) * K + blockIdx.y * 64 + q * 16;
    *(uint4*)d = o0;
    *(uint4*)(d + 8) = o1;
}

// ---------------- fused gate+up (all experts):  Hbuf[hrow] = silu(Xg@Wg) * (Xg@Wu) ----------------
template<bool PC>
__global__ __launch_bounds__(256) void gateup_kernel(
    const void* __restrict__ Bg_, const void* __restrict__ Bu_,
    const int* __restrict__ plan, const int* __restrict__ idx_list,
    const unsigned short* __restrict__ xb, unsigned short* __restrict__ Hbuf)
{
    constexpr int LDA = 72;
    __shared__ unsigned short Asm[128 * LDA];
    __shared__ unsigned short Bsm[2][64 * LDA];
    __shared__ int toks[128];

    if ((int)blockIdx.y >= plan[0]) return;
    int tbv = plan[16 + blockIdx.y];
    int e = tbv >> 16, mb = tbv & 0xffff;
    int hbase = plan[4 + e];
    int n_e = plan[5 + e] - hbase;
    int m0 = mb * 128;
    int n0 = blockIdx.x * 64;
    int tid = threadIdx.x, lane = tid & 63, wave = tid >> 6;
    int wm = wave >> 1, wn = wave & 1;

    if (tid < 128) {
        int r = m0 + tid;
        toks[tid] = idx_list[e * NT + ((r < n_e) ? r : 0)];
    }
    __syncthreads();

    v4f acc[2][4][2];
#pragma unroll
    for (int w = 0; w < 2; w++)
#pragma unroll
        for (int i = 0; i < 4; i++)
#pragma unroll
            for (int j = 0; j < 2; j++) acc[w][i][j] = (v4f){0.f, 0.f, 0.f, 0.f};

    int am = tid >> 1, ah = tid & 1;
    const unsigned short* Arow = xb + (size_t)toks[am] * HD;
    int brow = tid >> 3, bch = tid & 7;

    for (int k0 = 0; k0 < HD; k0 += 64) {
        {   // stage A
            const uint4* src = (const uint4*)(Arow + k0 + ah * 32);
            uint4* dst = (uint4*)(Asm + am * LDA + ah * 32);
#pragma unroll
            for (int j = 0; j < 4; j++) dst[j] = src[j];
        }
        if constexpr (PC) {   // stage B: coalesced bf16 rows (128B segments)
#pragma unroll
            for (int w = 0; w < 2; w++) {
                const unsigned short* wsl = (const unsigned short*)(w ? Bu_ : Bg_);
#pragma unroll
                for (int p = 0; p < 2; p++) {
                    int row = p * 32 + brow;
                    *(uint4*)(Bsm[w] + row * LDA + bch * 8) =
                        *(const uint4*)(wsl + ((size_t)e * FF + n0 + row) * HD + k0 + bch * 8);
                }
            }
        } else {              // stage B: fp32 -> bf16 transpose on the fly
            int n = (tid & 15) * 4, kg = tid >> 4;
#pragma unroll
            for (int w = 0; w < 2; w++) {
                const float* bp = (const float*)(w ? Bu_ : Bg_)
                    + (size_t)e * HD * FF + (size_t)(k0 + kg * 4) * FF + n0 + n;
                v4f rr[4];
#pragma unroll
                for (int kk = 0; kk < 4; kk++) rr[kk] = *(const v4f*)(bp + (size_t)kk * FF);
#pragma unroll
                for (int c = 0; c < 4; c++) {
                    uint2 p2;
                    p2.x = pk2(f2bf(rr[0][c]), f2bf(rr[1][c]));
                    p2.y = pk2(f2bf(rr[2][c]), f2bf(rr[3][c]));
                    *(uint2*)(Bsm[w] + (n + c) * LDA + kg * 4) = p2;
                }
            }
        }
        __syncthreads();
        {
            int q = lane >> 4, ln = lane & 15;
#pragma unroll
            for (int ks = 0; ks < 2; ks++) {
                v8s a[4], b[2][2];
#pragma unroll
                for (int i = 0; i < 4; i++)
                    a[i] = *(const v8s*)(Asm + (wm * 64 + i * 16 + ln) * LDA + ks * 32 + q * 8);
#pragma unroll
                for (int w = 0; w < 2; w++)
#pragma unroll
                    for (int j = 0; j < 2; j++)
                        b[w][j] = *(const v8s*)(Bsm[w] + (wn * 32 + j * 16 + ln) * LDA + ks * 32 + q * 8);
#pragma unroll
                for (int i = 0; i < 4; i++)
#pragma unroll
                    for (int j = 0; j < 2; j++) {
                        acc[0][i][j] = __builtin_amdgcn_mfma_f32_16x16x32_bf16(a[i], b[0][j], acc[0][i][j], 0, 0, 0);
                        acc[1][i][j] = __builtin_amdgcn_mfma_f32_16x16x32_bf16(a[i], b[1][j], acc[1][i][j], 0, 0, 0);
                    }
            }
        }
        __syncthreads();
    }

    int q = lane >> 4, ln = lane & 15;
#pragma unroll
    for (int i = 0; i < 4; i++)
#pragma unroll
        for (int j = 0; j < 2; j++)
#pragma unroll
            for (int r = 0; r < 4; r++) {
                int lm = wm * 64 + i * 16 + q * 4 + r;
                int gm = m0 + lm;
                int gn = n0 + wn * 32 + j * 16 + ln;
                if (gm < n_e) {
                    float g = acc[0][i][j][r];
                    float u = acc[1][i][j][r];
                    float sg = g / (1.f + __expf(-g));
                    Hbuf[(size_t)(hbase + gm) * FF + gn] = f2bf(sg * u);
                }
            }
}

// ---------------- down (all experts):  Dbuf[hrow] = Hbuf[hrow] @ Wd ----------------
template<bool PC>
__global__ __launch_bounds__(256) void down_kernel(
    const void* __restrict__ Bd_, const int* __restrict__ plan,
    const unsigned short* __restrict__ Hbuf, unsigned short* __restrict__ Dbuf)
{
    constexpr int LDA = 72;
    __shared__ unsigned short Asm[128 * LDA];
    __shared__ unsigned short Bsm[128 * LDA];

    if ((int)blockIdx.y >= plan[0]) return;
    int tbv = plan[16 + blockIdx.y];
    int e = tbv >> 16, mb = tbv & 0xffff;
    int hbase = plan[4 + e];
    int n_e = plan[5 + e] - hbase;
    int m0 = mb * 128;
    int n0 = blockIdx.x * 128;
    int tid = threadIdx.x, lane = tid & 63, wave = tid >> 6;
    int wm = wave >> 1, wn = wave & 1;

    v4f acc[4][4];
#pragma unroll
    for (int i = 0; i < 4; i++)
#pragma unroll
        for (int j = 0; j < 4; j++) acc[i][j] = (v4f){0.f, 0.f, 0.f, 0.f};

    int am = tid >> 1, ah = tid & 1;
    const unsigned short* Arow = Hbuf + (size_t)(hbase + m0 + am) * FF;
    int brow = tid >> 3, bch = tid & 7;

    for (int k0 = 0; k0 < FF; k0 += 64) {
        {
            const uint4* src = (const uint4*)(Arow + k0 + ah * 32);
            uint4* dst = (uint4*)(Asm + am * LDA + ah * 32);
#pragma unroll
            for (int j = 0; j < 4; j++) dst[j] = src[j];
        }
        if constexpr (PC) {
            const unsigned short* wsl = (const unsigned short*)Bd_;
#pragma unroll
            for (int p = 0; p < 4; p++) {
                int row = p * 32 + brow;
                *(uint4*)(Bsm + row * LDA + bch * 8) =
                    *(const uint4*)(wsl + ((size_t)e * HD + n0 + row) * FF + k0 + bch * 8);
            }
        } else {
            int n = (tid & 31) * 4, kg = tid >> 5;   // 128 cols, 8 k-rows each
            const float* bp = (const float*)Bd_
                + (size_t)e * FF * HD + (size_t)(k0 + kg * 8) * HD + n0 + n;
            v4f rr[8];
#pragma unroll
            for (int kk = 0; kk < 8; kk++) rr[kk] = *(const v4f*)(bp + (size_t)kk * HD);
#pragma unroll
            for (int c = 0; c < 4; c++) {
                uint4 pkd;
                pkd.x = pk2(f2bf(rr[0][c]), f2bf(rr[1][c]));
                pkd.y = pk2(f2bf(rr[2][c]), f2bf(rr[3][c]));
                pkd.z = pk2(f2bf(rr[4][c]), f2bf(rr[5][c]));
                pkd.w = pk2(f2bf(rr[6][c]), f2bf(rr[7][c]));
                *(uint4*)(Bsm + (n + c) * LDA + kg * 8) = pkd;
            }
        }
        __syncthreads();
        {
            int q = lane >> 4, ln = lane & 15;
#pragma unroll
            for (int ks = 0; ks < 2; ks++) {
                v8s a[4], b[4];
#pragma unroll
                for (int i = 0; i < 4; i++)
                    a[i] = *(const v8s*)(Asm + (wm * 64 + i * 16 + ln) * LDA + ks * 32 + q * 8);
#pragma unroll
                for (int j = 0; j < 4; j++)
                    b[j] = *(const v8s*)(Bsm + (wn * 64 + j * 16 + ln) * LDA + ks * 32 + q * 8);
#pragma unroll
                for (int i = 0; i < 4; i++)
#pragma unroll
                    for (int j = 0; j < 4; j++)
                        acc[i][j] = __builtin_amdgcn_mfma_f32_16x16x32_bf16(a[i], b[j], acc[i][j], 0, 0, 0);
            }
        }
        __syncthreads();
    }

    int q = lane >> 4, ln = lane & 15;
#pragma unroll
    for (int i = 0; i < 4; i++)
#pragma unroll
        for (int j = 0; j < 4; j++)
#pragma unroll
            for (int r = 0; r < 4; r++) {
                int lm = wm * 64 + i * 16 + q * 4 + r;
                int gm = m0 + lm;
                int gn = n0 + wn * 64 + j * 16 + ln;
                if (gm < n_e)
                    Dbuf[(size_t)(hbase + gm) * HD + gn] = f2bf(acc[i][j][r]);
            }
}

// ---------------- gather: out[t] = w1*Dbuf[row1] + w2*Dbuf[row2] ----------------
__global__ __launch_bounds__(256) void gather_kernel(
    const int* __restrict__ slot1, const float* __restrict__ w1a,
    const int* __restrict__ slot2, const float* __restrict__ w2a,
    const int* __restrict__ plan, const unsigned short* __restrict__ Dbuf,
    float* __restrict__ out)
{
    int t = blockIdx.x, c = threadIdx.x;
    int s1 = slot1[t], s2 = slot2[t];
    int h1 = plan[4 + (s1 >> 16)] + (s1 & 0xffff);
    int h2 = plan[4 + (s2 >> 16)] + (s2 & 0xffff);
    float a = w1a[t], b = w2a[t];
    ushort4 d1 = ((const ushort4*)(Dbuf + (size_t)h1 * HD))[c];
    ushort4 d2 = ((const ushort4*)(Dbuf + (size_t)h2 * HD))[c];
    v4f o;
    o[0] = a * bf2f(d1.x) + b * bf2f(d2.x);
    o[1] = a * bf2f(d1.y) + b * bf2f(d2.y);
    o[2] = a * bf2f(d1.z) + b * bf2f(d2.z);
    o[3] = a * bf2f(d1.w) + b * bf2f(d2.w);
    ((v4f*)(out + (size_t)t * HD))[c] = o;
}

extern "C" void kernel_launch(void* const* d_in, const int* in_sizes, int n_in,
                              void* d_out, int out_size, void* d_ws, size_t ws_size,
                              hipStream_t stream)
{
    const float* x  = (const float*)d_in[0];
    const float* wr = (const float*)d_in[1];
    const float* wg = (const float*)d_in[2];
    const float* wu = (const float*)d_in[3];
    const float* wd = (const float*)d_in[4];
    float* out = (float*)d_out;

    char* ws = (char*)d_ws;
    int*   cnt      = (int*)(ws + WS_CNT);
    float* pz       = (float*)(ws + WS_PZ);
    float* pp       = (float*)(ws + WS_PP);
    int*   plan     = (int*)(ws + WS_PLAN);
    int*   idx_list = (int*)(ws + WS_IDX);
    int*   slot1    = (int*)(ws + WS_SLOT1);
    float* w1a      = (float*)(ws + WS_W1);
    int*   slot2    = (int*)(ws + WS_SLOT2);
    float* w2a      = (float*)(ws + WS_W2);
    unsigned short* xb   = (unsigned short*)(ws + WS_XB);
    unsigned short* Hbuf = (unsigned short*)(ws + WS_HBUF);
    unsigned short* Dbuf = (unsigned short*)(ws + WS_DBUF);
    unsigned short* wgb  = (unsigned short*)(ws + WS_WGB);
    unsigned short* wub  = (unsigned short*)(ws + WS_WUB);
    unsigned short* wdb  = (unsigned short*)(ws + WS_WDB);

    bool pc = ws_size >= WS_PC_END;

    hipMemsetAsync(ws + WS_CNT, 0, 1024, stream);

    if (pc) {
        conv_kernel<HD, FF><<<dim3(FF / 64, HD / 64, NE), 256, 0, stream>>>(wg, wgb);
        conv_kernel<HD, FF><<<dim3(FF / 64, HD / 64, NE), 256, 0, stream>>>(wu, wub);
        conv_kernel<FF, HD><<<dim3(HD / 64, FF / 64, NE), 256, 0, stream>>>(wd, wdb);
    }

    router_kernel<<<NT / 4, 256, 0, stream>>>(x, wr, cnt, pz, pp, idx_list,
                                              slot1, w1a, slot2, w2a, xb);
    loss_plan_kernel<<<1, 256, 0, stream>>>(pz, pp, cnt, plan, out);

    // 136 m-blocks covers worst case: sum ceil(cnt_e/128) <= 128 + 8
    if (pc) {
        gateup_kernel<true><<<dim3(FF / 64, 136), 256, 0, stream>>>(
            wgb, wub, plan, idx_list, xb, Hbuf);
        down_kernel<true><<<dim3(HD / 128, 136), 256, 0, stream>>>(
            wdb, plan, Hbuf, Dbuf);
    } else {
        gateup_kernel<false><<<dim3(FF / 64, 136), 256, 0, stream>>>(
            wg, wu, plan, idx_list, xb, Hbuf);
        down_kernel<false><<<dim3(HD / 128, 136), 256, 0, stream>>>(
            wd, plan, Hbuf, Dbuf);
    }

    gather_kernel<<<NT, 256, 0, stream>>>(slot1, w1a, slot2, w2a, plan, Dbuf, out);
}